// Round 7
// baseline (548.512 us; speedup 1.0000x reference)
//
#include <hip/hip_runtime.h>
#include <hip/hip_cooperative_groups.h>

namespace cg = cooperative_groups;

// out[d] = sum_{e: dst[e]==d} x[src[e]]   (N=100k, E=1.6M, D=32 f32)
//
// Round-6 lesson: per-kernel work is fine but 5 serialized dispatches (incl.
// a 1-block scan kernel) cost ~launch-latency each. Fix: single cooperative
// kernel, 782 blocks x 512 threads (co-resident: 4 blk/CU, ~24KB LDS, <=64
// VGPR), 3 grid.sync()s. Phases: hist -> tile scan -> bucket scan -> scatter
// -> per-bucket sorted gather (round-6 body unchanged).

#define D_FEAT 32
#define BKT_SHIFT 7
#define BKT_NODES 128
#define MAX_NB 1024
#define NT 8                  // j-tiles for the 2-level rank scan
#define GCHUNK 2048           // entries per LDS pass (gather)
typedef unsigned int u32;

// ==================== fused cooperative kernel ====================

__global__ void __launch_bounds__(512, 8)
k_fused(const float* __restrict__ x, const int* __restrict__ src,
        const int* __restrict__ dst, u32* __restrict__ hist,
        u32* __restrict__ tilesum, u32* __restrict__ offs,
        u32* __restrict__ bin, float* __restrict__ out,
        int n_edges, int n_nodes, int nb, int npart, int chunk, int jtile) {
    __shared__ u32 sh_cnt[MAX_NB];        // hist (A) / cursors (C)
    __shared__ u32 sh_s[512];             // bucket scan (B2)
    __shared__ u32 s_ent[GCHUNK];
    __shared__ u32 s_srt[GCHUNK];
    __shared__ u32 s_off[BKT_NODES + 1];
    __shared__ u32 s_cur[BKT_NODES];
    __shared__ u32 s_scan[BKT_NODES];

    cg::grid_group grid = cg::this_grid();
    int t = threadIdx.x;
    int blk = blockIdx.x;

    // ---- Phase A: per-chunk histogram -> hist[blk][bucket] ----
    if (blk < npart) {
        for (int i = t; i < nb; i += 512) sh_cnt[i] = 0u;
        __syncthreads();
        int beg = blk * chunk, end = min(beg + chunk, n_edges);
        for (int e = beg + t; e < end; e += 512)
            atomicAdd(&sh_cnt[((u32)dst[e]) >> BKT_SHIFT], 1u);
        __syncthreads();
        u32* row = hist + (size_t)blk * nb;
        for (int i = t; i < nb; i += 512) row[i] = sh_cnt[i];
    }
    grid.sync();

    // ---- Phase B1: tile scan (blocks 0..NT-1), coalesced across buckets ----
    if (blk < NT) {
        int j0 = blk * jtile, j1 = min(j0 + jtile, npart);
        for (int b = t; b < nb; b += 512) {
            u32 run = 0u;
            for (int j = j0; j < j1; ++j) {
                u32 v = hist[(size_t)j * nb + b];
                hist[(size_t)j * nb + b] = run;
                run += v;
            }
            tilesum[(size_t)blk * nb + b] = run;
        }
    }
    grid.sync();

    // ---- Phase B2: bucket scan (block 0 only; 2 buckets per thread) ----
    if (blk == 0) {
        int b0 = 2 * t, b1 = 2 * t + 1;
        u32 r0 = 0u, r1 = 0u;
        if (b0 < nb) {
            for (int jt = 0; jt < NT; ++jt) {
                u32 v = tilesum[(size_t)jt * nb + b0];
                tilesum[(size_t)jt * nb + b0] = r0;
                r0 += v;
            }
        }
        if (b1 < nb) {
            for (int jt = 0; jt < NT; ++jt) {
                u32 v = tilesum[(size_t)jt * nb + b1];
                tilesum[(size_t)jt * nb + b1] = r1;
                r1 += v;
            }
        }
        u32 pair = r0 + r1;
        sh_s[t] = pair;
        __syncthreads();
        for (int off = 1; off < 512; off <<= 1) {
            u32 y = (t >= off) ? sh_s[t - off] : 0u;
            __syncthreads();
            if (t >= off) sh_s[t] += y;
            __syncthreads();
        }
        u32 ex = sh_s[t] - pair;   // exclusive pair base
        if (b0 < nb) {
            offs[b0] = ex;
            for (int jt = 0; jt < NT; ++jt) tilesum[(size_t)jt * nb + b0] += ex;
        }
        if (b1 < nb) {
            offs[b1] = ex + r0;
            for (int jt = 0; jt < NT; ++jt) tilesum[(size_t)jt * nb + b1] += ex + r0;
        }
        if (t == 0) offs[nb] = (u32)n_edges;
    }
    grid.sync();

    // ---- Phase C: scatter into block-private contiguous runs ----
    if (blk < npart) {
        int jt = blk / jtile;
        const u32* row = hist + (size_t)blk * nb;
        const u32* ts  = tilesum + (size_t)jt * nb;
        for (int i = t; i < nb; i += 512) sh_cnt[i] = row[i] + ts[i];
        __syncthreads();
        int beg = blk * chunk, end = min(beg + chunk, n_edges);
        for (int e = beg + t; e < end; e += 512) {
            u32 d = (u32)dst[e];
            u32 pos = atomicAdd(&sh_cnt[d >> BKT_SHIFT], 1u);
            bin[pos] = (u32)src[e] | ((d & (BKT_NODES - 1)) << 17);
        }
    }
    grid.sync();

    // ---- Phase D: gather, one bucket per block (round-6 body) ----
    int b = blk;
    if (b < nb) {
        int node0 = b * BKT_NODES;
        u32 beg = offs[b], end = offs[b + 1];
        const float4* x4 = (const float4*)x;
        int q = t & 7;
        int n0 = t >> 3;                       // 0..63; second node = n0+64
        float4 a0 = make_float4(0.f, 0.f, 0.f, 0.f);
        float4 a1 = make_float4(0.f, 0.f, 0.f, 0.f);

        for (u32 c0 = beg; c0 < end; c0 += GCHUNK) {
            int m = (int)min((u32)GCHUNK, end - c0);
            for (int i = t; i < m; i += 512) s_ent[i] = bin[c0 + i];
            if (t < BKT_NODES) s_cur[t] = 0u;
            __syncthreads();
            for (int i = t; i < m; i += 512) atomicAdd(&s_cur[s_ent[i] >> 17], 1u);
            __syncthreads();
            u32 v = 0u;
            if (t < BKT_NODES) { v = s_cur[t]; s_scan[t] = v; }
            __syncthreads();
            for (int off = 1; off < BKT_NODES; off <<= 1) {
                u32 y = 0u;
                if (t < BKT_NODES && t >= off) y = s_scan[t - off];
                __syncthreads();
                if (t < BKT_NODES && t >= off) s_scan[t] += y;
                __syncthreads();
            }
            if (t < BKT_NODES) { u32 ex = s_scan[t] - v; s_off[t] = ex; s_cur[t] = ex; }
            if (t == BKT_NODES - 1) s_off[BKT_NODES] = s_scan[BKT_NODES - 1];
            __syncthreads();
            for (int i = t; i < m; i += 512) {
                u32 p = s_ent[i];
                u32 pos = atomicAdd(&s_cur[p >> 17], 1u);
                s_srt[pos] = p & 0x1FFFFu;
            }
            __syncthreads();
            {
                u32 j1 = s_off[n0 + 1];
                for (u32 j = s_off[n0]; j < j1; ++j) {
                    float4 xv = x4[(size_t)s_srt[j] * 8 + q];
                    a0.x += xv.x; a0.y += xv.y; a0.z += xv.z; a0.w += xv.w;
                }
                u32 j3 = s_off[n0 + 65];
                for (u32 j = s_off[n0 + 64]; j < j3; ++j) {
                    float4 xv = x4[(size_t)s_srt[j] * 8 + q];
                    a1.x += xv.x; a1.y += xv.y; a1.z += xv.z; a1.w += xv.w;
                }
            }
            __syncthreads();
        }

        float4* o4 = (float4*)out;
        if (node0 + n0 < n_nodes)      o4[(size_t)node0 * 8 + t] = a0;
        if (node0 + n0 + 64 < n_nodes) o4[(size_t)node0 * 8 + 512 + t] = a1;
    }
}

// ==================== round-6 fallback kernels ====================

__global__ void __launch_bounds__(256)
k_hist(const int* __restrict__ dst, u32* __restrict__ hist,
       int n_edges, int nb, int chunk) {
    __shared__ u32 h[MAX_NB];
    for (int i = threadIdx.x; i < nb; i += 256) h[i] = 0u;
    __syncthreads();
    int beg = blockIdx.x * chunk;
    int end = min(beg + chunk, n_edges);
    for (int e = beg + threadIdx.x; e < end; e += 256)
        atomicAdd(&h[((u32)dst[e]) >> BKT_SHIFT], 1u);
    __syncthreads();
    u32* row = hist + (size_t)blockIdx.x * nb;
    for (int i = threadIdx.x; i < nb; i += 256) row[i] = h[i];
}

__global__ void __launch_bounds__(256)
k_tilescan(u32* __restrict__ hist, u32* __restrict__ tilesum,
           int nb, int nblk, int jtile) {
    int b = blockIdx.x * 256 + threadIdx.x;
    if (b >= nb) return;
    int jt = blockIdx.y;
    int j0 = jt * jtile, j1 = min(j0 + jtile, nblk);
    u32 run = 0u;
    for (int j = j0; j < j1; ++j) {
        u32 v = hist[(size_t)j * nb + b];
        hist[(size_t)j * nb + b] = run;
        run += v;
    }
    tilesum[(size_t)jt * nb + b] = run;
}

__global__ void __launch_bounds__(1024)
k_bucketscan(u32* __restrict__ tilesum, u32* __restrict__ offs,
             int nb, int ntiles, u32 total_edges) {
    __shared__ u32 s[1024];
    int t = threadIdx.x;
    u32 run = 0u;
    if (t < nb) {
        for (int jt = 0; jt < ntiles; ++jt) {
            u32 v = tilesum[(size_t)jt * nb + t];
            tilesum[(size_t)jt * nb + t] = run;
            run += v;
        }
    }
    s[t] = (t < nb) ? run : 0u;
    __syncthreads();
    for (int off = 1; off < 1024; off <<= 1) {
        u32 y = (t >= off) ? s[t - off] : 0u;
        __syncthreads();
        if (t >= off) s[t] += y;
        __syncthreads();
    }
    if (t < nb) {
        u32 ex = s[t] - run;
        offs[t] = ex;
        for (int jt = 0; jt < ntiles; ++jt)
            tilesum[(size_t)jt * nb + t] += ex;
    }
    if (t == 0) offs[nb] = total_edges;
}

__global__ void __launch_bounds__(256)
k_scatter(const int* __restrict__ src, const int* __restrict__ dst,
          const u32* __restrict__ hist, const u32* __restrict__ tilesum,
          u32* __restrict__ bin, int n_edges, int nb, int chunk, int jtile) {
    __shared__ u32 cur[MAX_NB];
    int j = blockIdx.x;
    int jt = j / jtile;
    const u32* row = hist + (size_t)j * nb;
    const u32* ts  = tilesum + (size_t)jt * nb;
    for (int i = threadIdx.x; i < nb; i += 256) cur[i] = row[i] + ts[i];
    __syncthreads();
    int beg = j * chunk;
    int end = min(beg + chunk, n_edges);
    for (int e = beg + threadIdx.x; e < end; e += 256) {
        u32 d = (u32)dst[e];
        u32 pos = atomicAdd(&cur[d >> BKT_SHIFT], 1u);
        bin[pos] = (u32)src[e] | ((d & (BKT_NODES - 1)) << 17);
    }
}

__global__ void __launch_bounds__(512)
k_gather(const float* __restrict__ x, const u32* __restrict__ offs,
         const u32* __restrict__ bin, float* __restrict__ out, int n_nodes) {
    __shared__ u32 s_ent[GCHUNK];
    __shared__ u32 s_srt[GCHUNK];
    __shared__ u32 s_off[BKT_NODES + 1];
    __shared__ u32 s_cur[BKT_NODES];
    __shared__ u32 s_scan[BKT_NODES];
    int b = blockIdx.x, t = threadIdx.x;
    int node0 = b * BKT_NODES;
    u32 beg = offs[b], end = offs[b + 1];
    const float4* x4 = (const float4*)x;
    int q = t & 7;
    int n0 = t >> 3;
    float4 a0 = make_float4(0.f, 0.f, 0.f, 0.f);
    float4 a1 = make_float4(0.f, 0.f, 0.f, 0.f);

    for (u32 c0 = beg; c0 < end; c0 += GCHUNK) {
        int m = (int)min((u32)GCHUNK, end - c0);
        for (int i = t; i < m; i += 512) s_ent[i] = bin[c0 + i];
        if (t < BKT_NODES) s_cur[t] = 0u;
        __syncthreads();
        for (int i = t; i < m; i += 512) atomicAdd(&s_cur[s_ent[i] >> 17], 1u);
        __syncthreads();
        u32 v = 0u;
        if (t < BKT_NODES) { v = s_cur[t]; s_scan[t] = v; }
        __syncthreads();
        for (int off = 1; off < BKT_NODES; off <<= 1) {
            u32 y = 0u;
            if (t < BKT_NODES && t >= off) y = s_scan[t - off];
            __syncthreads();
            if (t < BKT_NODES && t >= off) s_scan[t] += y;
            __syncthreads();
        }
        if (t < BKT_NODES) { u32 ex = s_scan[t] - v; s_off[t] = ex; s_cur[t] = ex; }
        if (t == BKT_NODES - 1) s_off[BKT_NODES] = s_scan[BKT_NODES - 1];
        __syncthreads();
        for (int i = t; i < m; i += 512) {
            u32 p = s_ent[i];
            u32 pos = atomicAdd(&s_cur[p >> 17], 1u);
            s_srt[pos] = p & 0x1FFFFu;
        }
        __syncthreads();
        {
            u32 j1 = s_off[n0 + 1];
            for (u32 j = s_off[n0]; j < j1; ++j) {
                float4 xv = x4[(size_t)s_srt[j] * 8 + q];
                a0.x += xv.x; a0.y += xv.y; a0.z += xv.z; a0.w += xv.w;
            }
            u32 j3 = s_off[n0 + 65];
            for (u32 j = s_off[n0 + 64]; j < j3; ++j) {
                float4 xv = x4[(size_t)s_srt[j] * 8 + q];
                a1.x += xv.x; a1.y += xv.y; a1.z += xv.z; a1.w += xv.w;
            }
        }
        __syncthreads();
    }

    float4* o4 = (float4*)out;
    if (node0 + n0 < n_nodes)      o4[(size_t)node0 * 8 + t] = a0;
    if (node0 + n0 + 64 < n_nodes) o4[(size_t)node0 * 8 + 512 + t] = a1;
}

// ---------------- last-resort fallback (round-1 atomic path) ----------------

__global__ void __launch_bounds__(256)
mp_zero_kernel(float* __restrict__ out, int n) {
    int i = blockIdx.x * blockDim.x + threadIdx.x;
    if (i < n) out[i] = 0.0f;
}

__global__ void __launch_bounds__(256)
mp_scatter_kernel(const float* __restrict__ x, const int* __restrict__ src,
                  const int* __restrict__ dst, float* __restrict__ out,
                  int n_edges) {
    int idx = blockIdx.x * blockDim.x + threadIdx.x;
    if (idx >= n_edges * 8) return;
    int e = idx >> 3;
    int c = idx & 7;
    const float4 v = *reinterpret_cast<const float4*>(x + (size_t)src[e] * D_FEAT + c * 4);
    float* o = out + (size_t)dst[e] * D_FEAT + c * 4;
    unsafeAtomicAdd(o + 0, v.x);
    unsafeAtomicAdd(o + 1, v.y);
    unsafeAtomicAdd(o + 2, v.z);
    unsafeAtomicAdd(o + 3, v.w);
}

// ==================== launch ====================

static void launch_round6_path(const float* x, const int* src, const int* dst,
                               float* out, int n_edges, int n_nodes, int nb,
                               void* d_ws, size_t ws_size, int out_size,
                               hipStream_t stream) {
    int chunk = 0, nblk = 0;
    const int cand[2] = {4096, 8192};
    for (int ci = 0; ci < 2; ++ci) {
        int c = cand[ci];
        int nbk = (n_edges + c - 1) / c;
        size_t nd = ((size_t)nbk * nb + (size_t)NT * nb + (nb + 1) + n_edges) * sizeof(u32);
        if (nd <= ws_size && nbk <= 4096) { chunk = c; nblk = nbk; break; }
    }
    bool ok = (chunk != 0) && (nb <= MAX_NB) && (n_nodes <= (1 << 17));
    if (!ok) {
        mp_zero_kernel<<<(out_size + 255) / 256, 256, 0, stream>>>(out, out_size);
        int total_thr = n_edges * 8;
        mp_scatter_kernel<<<(total_thr + 255) / 256, 256, 0, stream>>>(x, src, dst, out, n_edges);
        return;
    }
    u32* hist    = (u32*)d_ws;
    u32* tilesum = hist + (size_t)nblk * nb;
    u32* offs    = tilesum + (size_t)NT * nb;
    u32* bin     = offs + (nb + 1);
    int jtile = (nblk + NT - 1) / NT;
    dim3 tsgrid((nb + 255) / 256, NT);
    k_hist<<<nblk, 256, 0, stream>>>(dst, hist, n_edges, nb, chunk);
    k_tilescan<<<tsgrid, 256, 0, stream>>>(hist, tilesum, nb, nblk, jtile);
    k_bucketscan<<<1, 1024, 0, stream>>>(tilesum, offs, nb, NT, (u32)n_edges);
    k_scatter<<<nblk, 256, 0, stream>>>(src, dst, hist, tilesum, bin,
                                        n_edges, nb, chunk, jtile);
    k_gather<<<nb, 512, 0, stream>>>(x, offs, bin, out, n_nodes);
}

extern "C" void kernel_launch(void* const* d_in, const int* in_sizes, int n_in,
                              void* d_out, int out_size, void* d_ws, size_t ws_size,
                              hipStream_t stream) {
    const float* x = (const float*)d_in[0];
    const int* edge_index = (const int*)d_in[1];
    int n_edges = in_sizes[1] / 2;
    const int* src = edge_index;            // row 0: source j
    const int* dst = edge_index + n_edges;  // row 1: target i
    float* out = (float*)d_out;
    int n_nodes = out_size / D_FEAT;

    int nb = (n_nodes + BKT_NODES - 1) >> BKT_SHIFT;     // 782

    bool shape_ok = (nb <= MAX_NB) && (nb <= 1024) && (n_nodes <= (1 << 17));

    // Choose npart (partition chunk count) so hist matrix fits ws.
    int npart = 0;
    if (shape_ok) {
        int candn[3] = {nb, (nb + 1) / 2, (nb + 3) / 4};
        for (int ci = 0; ci < 3; ++ci) {
            int np = candn[ci];
            if (np < NT) np = NT;
            size_t nd = ((size_t)np * nb + (size_t)NT * nb + (nb + 1) + n_edges) * sizeof(u32);
            if (nd <= ws_size) { npart = np; break; }
        }
    }

    if (npart > 0) {
        u32* hist    = (u32*)d_ws;
        u32* tilesum = hist + (size_t)npart * nb;
        u32* offs    = tilesum + (size_t)NT * nb;
        u32* bin     = offs + (nb + 1);
        int chunk = (n_edges + npart - 1) / npart;
        int jtile = (npart + NT - 1) / NT;

        void* args[] = {
            (void*)&x, (void*)&src, (void*)&dst, (void*)&hist, (void*)&tilesum,
            (void*)&offs, (void*)&bin, (void*)&out, (void*)&n_edges,
            (void*)&n_nodes, (void*)&nb, (void*)&npart, (void*)&chunk, (void*)&jtile
        };
        hipError_t err = hipLaunchCooperativeKernel(
            reinterpret_cast<const void*>(k_fused), dim3(nb), dim3(512),
            args, 0, stream);
        if (err == hipSuccess) return;
        (void)hipGetLastError();   // clear sticky error, fall through
    }

    launch_round6_path(x, src, dst, out, n_edges, n_nodes, nb,
                       d_ws, ws_size, out_size, stream);
}

// Round 8
// 133.446 us; speedup vs baseline: 4.1104x; 4.1104x over previous
//
#include <hip/hip_runtime.h>

// out[d] = sum_{e: dst[e]==d} x[src[e]]   (N=100k, E=1.6M, D=32 f32)
//
// Round-7 lesson: cooperative grid.sync() on gfx950 = disaster (475us, 98%
// idle: cross-XCD barrier drain + spin while 1-8 blocks work). Keep separate
// kernels but remove phases: deterministic fixed-capacity sub-bins kill the
// hist-matrix scan pipeline entirely. bin[blk][bucket][CAP]: each scatter
// block places edges in its private region via LDS cursors only (no global
// RMW, no scans). Rare overflow -> global list, replayed by gather. Pipeline:
// memset(4B) + k_scatter2 + k_gather2.

#define D_FEAT 32
#define BKT_SHIFT 7
#define BKT_NODES 128
#define MAX_NB 1024
#define ECAP 4096             // packed entries per gather flush
#define OVFCAP 65536
#define NT 8                  // round-6 fallback tile count
typedef unsigned int u32;

// ==================== primary path ====================

// One block per 'chunk' edges. Pass 1: LDS histogram -> cnt[blk][b] (coalesced).
// Pass 2: LDS cursors, place packed (src | dlocal<<17) into private sub-bins.
__global__ void __launch_bounds__(512)
k_scatter2(const int* __restrict__ src, const int* __restrict__ dst,
           u32* __restrict__ cnt, u32* __restrict__ bin,
           u32* __restrict__ ovf, u32* __restrict__ ovf_cnt,
           int n_edges, int nb, int chunk, int capsh) {
    __shared__ u32 c_l[MAX_NB];
    int blk = blockIdx.x, t = threadIdx.x;
    int cap = 1 << capsh;
    for (int i = t; i < nb; i += 512) c_l[i] = 0u;
    __syncthreads();
    int beg = blk * chunk, end = min(beg + chunk, n_edges);
    for (int e = beg + t; e < end; e += 512)
        atomicAdd(&c_l[((u32)dst[e]) >> BKT_SHIFT], 1u);
    __syncthreads();
    u32* row = cnt + (size_t)blk * nb;
    for (int i = t; i < nb; i += 512) row[i] = c_l[i];
    __syncthreads();
    for (int i = t; i < nb; i += 512) c_l[i] = 0u;
    __syncthreads();
    for (int e = beg + t; e < end; e += 512) {
        u32 d = (u32)dst[e];
        u32 b = d >> BKT_SHIFT;
        u32 pos = atomicAdd(&c_l[b], 1u);            // LDS-only RMW
        u32 packed = (u32)src[e] | ((d & (BKT_NODES - 1)) << 17);
        if (pos < (u32)cap) {
            bin[(((size_t)blk * nb + b) << capsh) + pos] = packed;
        } else {
            u32 g = atomicAdd(ovf_cnt, 1u);          // ~never taken
            if (g < OVFCAP) { ovf[2 * g] = packed; ovf[2 * g + 1] = b; }
        }
    }
}

// One block per bucket. Load sub-bin counts (L2-hot), LDS-scan, pack sub-bins
// into s_ent windows of <=ECAP, then sort-by-dlocal + register accumulate.
__global__ void __launch_bounds__(512)
k_gather2(const float* __restrict__ x, const u32* __restrict__ cnt,
          const u32* __restrict__ bin, const u32* __restrict__ ovf,
          const u32* __restrict__ ovf_cnt, float* __restrict__ out,
          int n_nodes, int nb, int nsub, int capsh) {
    __shared__ u32 s_cnt[512];
    __shared__ u32 s_sb[512];
    __shared__ u32 s_base[513];
    __shared__ u32 s_ent[ECAP];
    __shared__ u32 s_srt[ECAP];
    __shared__ u32 s_off[BKT_NODES + 1];
    __shared__ u32 s_cur[BKT_NODES];
    __shared__ u32 s_scan[BKT_NODES];
    int b = blockIdx.x, t = threadIdx.x;
    int cap = 1 << capsh;
    int node0 = b * BKT_NODES;
    const float4* x4 = (const float4*)x;
    int q = t & 7;
    int n0 = t >> 3;                       // nodes n0 and n0+64
    float4 a0 = make_float4(0.f, 0.f, 0.f, 0.f);
    float4 a1 = make_float4(0.f, 0.f, 0.f, 0.f);

    // counts (clamped to cap; excess lives in ovf) + exclusive scan
    u32 c = 0u;
    if (t < nsub) c = min(cnt[(size_t)t * nb + b], (u32)cap);
    s_cnt[t] = c;
    s_sb[t] = c;
    __syncthreads();
    for (int off = 1; off < 512; off <<= 1) {
        u32 y = (t >= off) ? s_sb[t - off] : 0u;
        __syncthreads();
        if (t >= off) s_sb[t] += y;
        __syncthreads();
    }
    s_base[t] = s_sb[t] - c;               // exclusive
    if (t == 511) s_base[512] = s_sb[511];
    __syncthreads();
    // (s_base[j] for j>nsub unused; s_base[nsub] correct since c=0 beyond)

    int subA = 0;
    u32 baseA = 0u;
    while (subA < nsub) {
        // uniform binary search: largest subB with base[subB]-baseA <= ECAP
        int lo = subA + 1, hi = nsub;
        while (lo < hi) {
            int mid = (lo + hi + 1) >> 1;
            if (s_base[mid] - baseA <= (u32)ECAP) lo = mid; else hi = mid - 1;
        }
        int subB = lo;
        int m = (int)(s_base[subB] - baseA);

        // pack sub-bins [subA,subB) into s_ent[0..m)
        for (int i = t; i < (subB - subA) << capsh; i += 512) {
            int sub = subA + (i >> capsh);
            int slot = i & (cap - 1);
            if (slot < (int)s_cnt[sub])
                s_ent[(s_base[sub] - baseA) + slot] =
                    bin[(((size_t)sub * nb + b) << capsh) + slot];
        }
        if (t < BKT_NODES) s_cur[t] = 0u;
        __syncthreads();

        // sort by dlocal: count, scan(128), rank
        for (int i = t; i < m; i += 512) atomicAdd(&s_cur[s_ent[i] >> 17], 1u);
        __syncthreads();
        u32 v = 0u;
        if (t < BKT_NODES) { v = s_cur[t]; s_scan[t] = v; }
        __syncthreads();
        for (int off = 1; off < BKT_NODES; off <<= 1) {
            u32 y = 0u;
            if (t < BKT_NODES && t >= off) y = s_scan[t - off];
            __syncthreads();
            if (t < BKT_NODES && t >= off) s_scan[t] += y;
            __syncthreads();
        }
        if (t < BKT_NODES) { u32 ex = s_scan[t] - v; s_off[t] = ex; s_cur[t] = ex; }
        if (t == BKT_NODES - 1) s_off[BKT_NODES] = s_scan[BKT_NODES - 1];
        __syncthreads();
        for (int i = t; i < m; i += 512) {
            u32 p = s_ent[i];
            u32 pos = atomicAdd(&s_cur[p >> 17], 1u);
            s_srt[pos] = p & 0x1FFFFu;
        }
        __syncthreads();

        // accumulate: 8 lanes share one 128B x-row
        {
            u32 j1 = s_off[n0 + 1];
            for (u32 j = s_off[n0]; j < j1; ++j) {
                float4 xv = x4[(size_t)s_srt[j] * 8 + q];
                a0.x += xv.x; a0.y += xv.y; a0.z += xv.z; a0.w += xv.w;
            }
            u32 j3 = s_off[n0 + 65];
            for (u32 j = s_off[n0 + 64]; j < j3; ++j) {
                float4 xv = x4[(size_t)s_srt[j] * 8 + q];
                a1.x += xv.x; a1.y += xv.y; a1.z += xv.z; a1.w += xv.w;
            }
        }
        __syncthreads();
        subA = subB;
        baseA = s_base[subB];
    }

    // replay overflow list (normally empty)
    u32 novf = min(*ovf_cnt, (u32)OVFCAP);
    for (u32 i = 0; i < novf; ++i) {
        if (ovf[2 * i + 1] == (u32)b) {
            u32 p = ovf[2 * i];
            u32 dl = p >> 17;
            if (dl == (u32)n0 || dl == (u32)(n0 + 64)) {
                float4 xv = x4[(size_t)(p & 0x1FFFFu) * 8 + q];
                if (dl == (u32)n0) { a0.x += xv.x; a0.y += xv.y; a0.z += xv.z; a0.w += xv.w; }
                else               { a1.x += xv.x; a1.y += xv.y; a1.z += xv.z; a1.w += xv.w; }
            }
        }
    }

    float4* o4 = (float4*)out;
    if (node0 + n0 < n_nodes)      o4[(size_t)node0 * 8 + t] = a0;
    if (node0 + n0 + 64 < n_nodes) o4[(size_t)node0 * 8 + 512 + t] = a1;
}

// ==================== round-6 fallback kernels ====================

__global__ void __launch_bounds__(256)
k_hist(const int* __restrict__ dst, u32* __restrict__ hist,
       int n_edges, int nb, int chunk) {
    __shared__ u32 h[MAX_NB];
    for (int i = threadIdx.x; i < nb; i += 256) h[i] = 0u;
    __syncthreads();
    int beg = blockIdx.x * chunk;
    int end = min(beg + chunk, n_edges);
    for (int e = beg + threadIdx.x; e < end; e += 256)
        atomicAdd(&h[((u32)dst[e]) >> BKT_SHIFT], 1u);
    __syncthreads();
    u32* row = hist + (size_t)blockIdx.x * nb;
    for (int i = threadIdx.x; i < nb; i += 256) row[i] = h[i];
}

__global__ void __launch_bounds__(256)
k_tilescan(u32* __restrict__ hist, u32* __restrict__ tilesum,
           int nb, int nblk, int jtile) {
    int b = blockIdx.x * 256 + threadIdx.x;
    if (b >= nb) return;
    int jt = blockIdx.y;
    int j0 = jt * jtile, j1 = min(j0 + jtile, nblk);
    u32 run = 0u;
    for (int j = j0; j < j1; ++j) {
        u32 v = hist[(size_t)j * nb + b];
        hist[(size_t)j * nb + b] = run;
        run += v;
    }
    tilesum[(size_t)jt * nb + b] = run;
}

__global__ void __launch_bounds__(1024)
k_bucketscan(u32* __restrict__ tilesum, u32* __restrict__ offs,
             int nb, int ntiles, u32 total_edges) {
    __shared__ u32 s[1024];
    int t = threadIdx.x;
    u32 run = 0u;
    if (t < nb) {
        for (int jt = 0; jt < ntiles; ++jt) {
            u32 v = tilesum[(size_t)jt * nb + t];
            tilesum[(size_t)jt * nb + t] = run;
            run += v;
        }
    }
    s[t] = (t < nb) ? run : 0u;
    __syncthreads();
    for (int off = 1; off < 1024; off <<= 1) {
        u32 y = (t >= off) ? s[t - off] : 0u;
        __syncthreads();
        if (t >= off) s[t] += y;
        __syncthreads();
    }
    if (t < nb) {
        u32 ex = s[t] - run;
        offs[t] = ex;
        for (int jt = 0; jt < ntiles; ++jt)
            tilesum[(size_t)jt * nb + t] += ex;
    }
    if (t == 0) offs[nb] = total_edges;
}

__global__ void __launch_bounds__(256)
k_scatter(const int* __restrict__ src, const int* __restrict__ dst,
          const u32* __restrict__ hist, const u32* __restrict__ tilesum,
          u32* __restrict__ bin, int n_edges, int nb, int chunk, int jtile) {
    __shared__ u32 cur[MAX_NB];
    int j = blockIdx.x;
    int jt = j / jtile;
    const u32* row = hist + (size_t)j * nb;
    const u32* ts  = tilesum + (size_t)jt * nb;
    for (int i = threadIdx.x; i < nb; i += 256) cur[i] = row[i] + ts[i];
    __syncthreads();
    int beg = j * chunk;
    int end = min(beg + chunk, n_edges);
    for (int e = beg + threadIdx.x; e < end; e += 256) {
        u32 d = (u32)dst[e];
        u32 pos = atomicAdd(&cur[d >> BKT_SHIFT], 1u);
        bin[pos] = (u32)src[e] | ((d & (BKT_NODES - 1)) << 17);
    }
}

__global__ void __launch_bounds__(512)
k_gather(const float* __restrict__ x, const u32* __restrict__ offs,
         const u32* __restrict__ bin, float* __restrict__ out, int n_nodes) {
    __shared__ u32 s_ent[2048];
    __shared__ u32 s_srt[2048];
    __shared__ u32 s_off[BKT_NODES + 1];
    __shared__ u32 s_cur[BKT_NODES];
    __shared__ u32 s_scan[BKT_NODES];
    int b = blockIdx.x, t = threadIdx.x;
    int node0 = b * BKT_NODES;
    u32 beg = offs[b], end = offs[b + 1];
    const float4* x4 = (const float4*)x;
    int q = t & 7;
    int n0 = t >> 3;
    float4 a0 = make_float4(0.f, 0.f, 0.f, 0.f);
    float4 a1 = make_float4(0.f, 0.f, 0.f, 0.f);

    for (u32 c0 = beg; c0 < end; c0 += 2048) {
        int m = (int)min((u32)2048, end - c0);
        for (int i = t; i < m; i += 512) s_ent[i] = bin[c0 + i];
        if (t < BKT_NODES) s_cur[t] = 0u;
        __syncthreads();
        for (int i = t; i < m; i += 512) atomicAdd(&s_cur[s_ent[i] >> 17], 1u);
        __syncthreads();
        u32 v = 0u;
        if (t < BKT_NODES) { v = s_cur[t]; s_scan[t] = v; }
        __syncthreads();
        for (int off = 1; off < BKT_NODES; off <<= 1) {
            u32 y = 0u;
            if (t < BKT_NODES && t >= off) y = s_scan[t - off];
            __syncthreads();
            if (t < BKT_NODES && t >= off) s_scan[t] += y;
            __syncthreads();
        }
        if (t < BKT_NODES) { u32 ex = s_scan[t] - v; s_off[t] = ex; s_cur[t] = ex; }
        if (t == BKT_NODES - 1) s_off[BKT_NODES] = s_scan[BKT_NODES - 1];
        __syncthreads();
        for (int i = t; i < m; i += 512) {
            u32 p = s_ent[i];
            u32 pos = atomicAdd(&s_cur[p >> 17], 1u);
            s_srt[pos] = p & 0x1FFFFu;
        }
        __syncthreads();
        {
            u32 j1 = s_off[n0 + 1];
            for (u32 j = s_off[n0]; j < j1; ++j) {
                float4 xv = x4[(size_t)s_srt[j] * 8 + q];
                a0.x += xv.x; a0.y += xv.y; a0.z += xv.z; a0.w += xv.w;
            }
            u32 j3 = s_off[n0 + 65];
            for (u32 j = s_off[n0 + 64]; j < j3; ++j) {
                float4 xv = x4[(size_t)s_srt[j] * 8 + q];
                a1.x += xv.x; a1.y += xv.y; a1.z += xv.z; a1.w += xv.w;
            }
        }
        __syncthreads();
    }

    float4* o4 = (float4*)out;
    if (node0 + n0 < n_nodes)      o4[(size_t)node0 * 8 + t] = a0;
    if (node0 + n0 + 64 < n_nodes) o4[(size_t)node0 * 8 + 512 + t] = a1;
}

// ---------------- last-resort fallback (round-1 atomic path) ----------------

__global__ void __launch_bounds__(256)
mp_zero_kernel(float* __restrict__ out, int n) {
    int i = blockIdx.x * blockDim.x + threadIdx.x;
    if (i < n) out[i] = 0.0f;
}

__global__ void __launch_bounds__(256)
mp_scatter_kernel(const float* __restrict__ x, const int* __restrict__ src,
                  const int* __restrict__ dst, float* __restrict__ out,
                  int n_edges) {
    int idx = blockIdx.x * blockDim.x + threadIdx.x;
    if (idx >= n_edges * 8) return;
    int e = idx >> 3;
    int c = idx & 7;
    const float4 v = *reinterpret_cast<const float4*>(x + (size_t)src[e] * D_FEAT + c * 4);
    float* o = out + (size_t)dst[e] * D_FEAT + c * 4;
    unsafeAtomicAdd(o + 0, v.x);
    unsafeAtomicAdd(o + 1, v.y);
    unsafeAtomicAdd(o + 2, v.z);
    unsafeAtomicAdd(o + 3, v.w);
}

// ==================== launch ====================

static void launch_round6_path(const float* x, const int* src, const int* dst,
                               float* out, int n_edges, int n_nodes, int nb,
                               void* d_ws, size_t ws_size, int out_size,
                               hipStream_t stream) {
    int chunk = 0, nblk = 0;
    const int cand[2] = {4096, 8192};
    for (int ci = 0; ci < 2; ++ci) {
        int c = cand[ci];
        int nbk = (n_edges + c - 1) / c;
        size_t nd = ((size_t)nbk * nb + (size_t)NT * nb + (nb + 1) + n_edges) * sizeof(u32);
        if (nd <= ws_size && nbk <= 4096) { chunk = c; nblk = nbk; break; }
    }
    bool ok = (chunk != 0) && (nb <= MAX_NB) && (n_nodes <= (1 << 17));
    if (!ok) {
        mp_zero_kernel<<<(out_size + 255) / 256, 256, 0, stream>>>(out, out_size);
        int total_thr = n_edges * 8;
        mp_scatter_kernel<<<(total_thr + 255) / 256, 256, 0, stream>>>(x, src, dst, out, n_edges);
        return;
    }
    u32* hist    = (u32*)d_ws;
    u32* tilesum = hist + (size_t)nblk * nb;
    u32* offs    = tilesum + (size_t)NT * nb;
    u32* bin     = offs + (nb + 1);
    int jtile = (nblk + NT - 1) / NT;
    dim3 tsgrid((nb + 255) / 256, NT);
    k_hist<<<nblk, 256, 0, stream>>>(dst, hist, n_edges, nb, chunk);
    k_tilescan<<<tsgrid, 256, 0, stream>>>(hist, tilesum, nb, nblk, jtile);
    k_bucketscan<<<1, 1024, 0, stream>>>(tilesum, offs, nb, NT, (u32)n_edges);
    k_scatter<<<nblk, 256, 0, stream>>>(src, dst, hist, tilesum, bin,
                                        n_edges, nb, chunk, jtile);
    k_gather<<<nb, 512, 0, stream>>>(x, offs, bin, out, n_nodes);
}

extern "C" void kernel_launch(void* const* d_in, const int* in_sizes, int n_in,
                              void* d_out, int out_size, void* d_ws, size_t ws_size,
                              hipStream_t stream) {
    const float* x = (const float*)d_in[0];
    const int* edge_index = (const int*)d_in[1];
    int n_edges = in_sizes[1] / 2;
    const int* src = edge_index;            // row 0: source j
    const int* dst = edge_index + n_edges;  // row 1: target i
    float* out = (float*)d_out;
    int n_nodes = out_size / D_FEAT;

    int nb = (n_nodes + BKT_NODES - 1) >> BKT_SHIFT;     // 782

    // Primary: deterministic sub-bin path. Try (chunk,capsh) = (4096,5) then (8192,6).
    if (nb <= MAX_NB && n_nodes <= (1 << 17)) {
        const int ccand[2] = {4096, 8192};
        const int scand[2] = {5, 6};
        for (int ci = 0; ci < 2; ++ci) {
            int chunk = ccand[ci], capsh = scand[ci];
            int nsub = (n_edges + chunk - 1) / chunk;
            if (nsub > 512) continue;
            size_t need = ((size_t)nsub * nb                     // cnt
                           + 16                                  // ovf_cnt (padded)
                           + 2 * (size_t)OVFCAP                  // ovf list
                           + (((size_t)nsub * nb) << capsh))     // bin
                          * sizeof(u32);
            if (need > ws_size) continue;

            u32* cnt     = (u32*)d_ws;
            u32* ovf_cnt = cnt + (size_t)nsub * nb;
            u32* ovf     = ovf_cnt + 16;
            u32* bin     = ovf + 2 * (size_t)OVFCAP;

            hipMemsetAsync(ovf_cnt, 0, sizeof(u32), stream);
            k_scatter2<<<nsub, 512, 0, stream>>>(src, dst, cnt, bin, ovf, ovf_cnt,
                                                 n_edges, nb, chunk, capsh);
            k_gather2<<<nb, 512, 0, stream>>>(x, cnt, bin, ovf, ovf_cnt, out,
                                              n_nodes, nb, nsub, capsh);
            return;
        }
    }

    launch_round6_path(x, src, dst, out, n_edges, n_nodes, nb,
                       d_ws, ws_size, out_size, stream);
}

// Round 9
// 125.793 us; speedup vs baseline: 4.3604x; 1.0608x over previous
//
#include <hip/hip_runtime.h>

// out[d] = sum_{e: dst[e]==d} x[src[e]]   (N=100k, E=1.6M, D=32 f32)
//
// Round-8 lesson: deterministic sub-bins work (133us) but scatter still does
// a redundant histogram pass (cursor finals ARE the counts) and gather reads
// bin as 391 scattered 128B islands per bucket. Round 9: single-pass scatter,
// bucket-major bin (sequential gather stream), uint4 packing, unrolled
// accumulate.

#define D_FEAT 32
#define BKT_SHIFT 7
#define BKT_NODES 128
#define MAX_NB 1024
#define CAPSH 5               // 32 slots per sub-bin
#define ECAP 4096             // packed entries per gather flush
#define OVFCAP 65536
typedef unsigned int u32;

// Single pass: place packed (src | dlocal<<17) into bucket-major private
// sub-bins via LDS cursors; final cursor values are the counts.
__global__ void __launch_bounds__(512)
k_scatter3(const int* __restrict__ src, const int* __restrict__ dst,
           u32* __restrict__ cnt, u32* __restrict__ bin,
           u32* __restrict__ ovf, u32* __restrict__ ovf_cnt,
           int n_edges, int nb, int nsub, int chunk) {
    __shared__ u32 c_l[MAX_NB];
    int blk = blockIdx.x, t = threadIdx.x;
    for (int i = t; i < nb; i += 512) c_l[i] = 0u;
    __syncthreads();
    int beg = blk * chunk, end = min(beg + chunk, n_edges);
    for (int e = beg + t; e < end; e += 512) {
        u32 d = (u32)dst[e];
        u32 b = d >> BKT_SHIFT;
        u32 pos = atomicAdd(&c_l[b], 1u);            // LDS-only RMW
        u32 packed = (u32)src[e] | ((d & (BKT_NODES - 1)) << 17);
        if (pos < (1u << CAPSH)) {
            bin[(((size_t)b * nsub + blk) << CAPSH) + pos] = packed;  // bucket-major
        } else {
            u32 g = atomicAdd(ovf_cnt, 1u);          // ~never taken
            if (g < OVFCAP) { ovf[2 * g] = packed; ovf[2 * g + 1] = b; }
        }
    }
    __syncthreads();
    u32* row = cnt + (size_t)blk * nb;
    for (int i = t; i < nb; i += 512) row[i] = c_l[i];   // coalesced
}

// One block per bucket. Sub-bin counts -> LDS scan -> pack (uint4, sequential
// stream) -> sort by dlocal -> register accumulate (2-way unrolled).
__global__ void __launch_bounds__(512)
k_gather3(const float* __restrict__ x, const u32* __restrict__ cnt,
          const u32* __restrict__ bin, const u32* __restrict__ ovf,
          const u32* __restrict__ ovf_cnt, float* __restrict__ out,
          int n_nodes, int nb, int nsub) {
    __shared__ u32 s_cnt[512];
    __shared__ u32 s_sb[512];
    __shared__ u32 s_base[513];
    __shared__ u32 s_ent[ECAP];
    __shared__ u32 s_srt[ECAP];
    __shared__ u32 s_off[BKT_NODES + 1];
    __shared__ u32 s_cur[BKT_NODES];
    __shared__ u32 s_scan[BKT_NODES];
    int b = blockIdx.x, t = threadIdx.x;
    int node0 = b * BKT_NODES;
    const float4* x4 = (const float4*)x;
    const uint4* bin4 = (const uint4*)bin;
    int q = t & 7;
    int n0 = t >> 3;                       // nodes n0 and n0+64
    float4 a0 = make_float4(0.f, 0.f, 0.f, 0.f);
    float4 a1 = make_float4(0.f, 0.f, 0.f, 0.f);

    // clamped counts + exclusive scan over sub-bins
    u32 c = 0u;
    if (t < nsub) c = min(cnt[(size_t)t * nb + b], 1u << CAPSH);
    s_cnt[t] = c;
    s_sb[t] = c;
    __syncthreads();
    for (int off = 1; off < 512; off <<= 1) {
        u32 y = (t >= off) ? s_sb[t - off] : 0u;
        __syncthreads();
        if (t >= off) s_sb[t] += y;
        __syncthreads();
    }
    s_base[t] = s_sb[t] - c;               // exclusive
    if (t == 511) s_base[512] = s_sb[511];
    __syncthreads();

    int subA = 0;
    u32 baseA = 0u;
    while (subA < nsub) {
        // largest subB with base[subB]-baseA <= ECAP (uniform binary search)
        int lo = subA + 1, hi = nsub;
        while (lo < hi) {
            int mid = (lo + hi + 1) >> 1;
            if (s_base[mid] - baseA <= (u32)ECAP) lo = mid; else hi = mid - 1;
        }
        int subB = lo;
        int m = (int)(s_base[subB] - baseA);

        // pack sub-bins [subA,subB): sequential uint4 stream
        {
            int quads = (subB - subA) << (CAPSH - 2);
            size_t qbase = ((size_t)b * nsub + subA) << (CAPSH - 2);
            for (int i = t; i < quads; i += 512) {
                int sub = subA + (i >> (CAPSH - 2));
                int k4 = i & ((1 << (CAPSH - 2)) - 1);
                int slot0 = k4 << 2;
                u32 cn = s_cnt[sub];
                if ((u32)slot0 < cn) {
                    uint4 v = bin4[qbase + i];
                    u32 base = (s_base[sub] - baseA) + slot0;
                    s_ent[base] = v.x;
                    if ((u32)(slot0 + 1) < cn) s_ent[base + 1] = v.y;
                    if ((u32)(slot0 + 2) < cn) s_ent[base + 2] = v.z;
                    if ((u32)(slot0 + 3) < cn) s_ent[base + 3] = v.w;
                }
            }
        }
        if (t < BKT_NODES) s_cur[t] = 0u;
        __syncthreads();

        // sort by dlocal: count, scan(128), rank
        for (int i = t; i < m; i += 512) atomicAdd(&s_cur[s_ent[i] >> 17], 1u);
        __syncthreads();
        u32 v = 0u;
        if (t < BKT_NODES) { v = s_cur[t]; s_scan[t] = v; }
        __syncthreads();
        for (int off = 1; off < BKT_NODES; off <<= 1) {
            u32 y = 0u;
            if (t < BKT_NODES && t >= off) y = s_scan[t - off];
            __syncthreads();
            if (t < BKT_NODES && t >= off) s_scan[t] += y;
            __syncthreads();
        }
        if (t < BKT_NODES) { u32 ex = s_scan[t] - v; s_off[t] = ex; s_cur[t] = ex; }
        if (t == BKT_NODES - 1) s_off[BKT_NODES] = s_scan[BKT_NODES - 1];
        __syncthreads();
        for (int i = t; i < m; i += 512) {
            u32 p = s_ent[i];
            u32 pos = atomicAdd(&s_cur[p >> 17], 1u);
            s_srt[pos] = p & 0x1FFFFu;
        }
        __syncthreads();

        // accumulate: 8 lanes share one 128B x-row; 2-way unroll for MLP
        {
            u32 j = s_off[n0], j1 = s_off[n0 + 1];
            for (; j + 1 < j1; j += 2) {
                float4 xa = x4[(size_t)s_srt[j] * 8 + q];
                float4 xb = x4[(size_t)s_srt[j + 1] * 8 + q];
                a0.x += xa.x; a0.y += xa.y; a0.z += xa.z; a0.w += xa.w;
                a0.x += xb.x; a0.y += xb.y; a0.z += xb.z; a0.w += xb.w;
            }
            if (j < j1) {
                float4 xa = x4[(size_t)s_srt[j] * 8 + q];
                a0.x += xa.x; a0.y += xa.y; a0.z += xa.z; a0.w += xa.w;
            }
            j = s_off[n0 + 64]; j1 = s_off[n0 + 65];
            for (; j + 1 < j1; j += 2) {
                float4 xa = x4[(size_t)s_srt[j] * 8 + q];
                float4 xb = x4[(size_t)s_srt[j + 1] * 8 + q];
                a1.x += xa.x; a1.y += xa.y; a1.z += xa.z; a1.w += xa.w;
                a1.x += xb.x; a1.y += xb.y; a1.z += xb.z; a1.w += xb.w;
            }
            if (j < j1) {
                float4 xa = x4[(size_t)s_srt[j] * 8 + q];
                a1.x += xa.x; a1.y += xa.y; a1.z += xa.z; a1.w += xa.w;
            }
        }
        __syncthreads();
        subA = subB;
        baseA = s_base[subB];
    }

    // replay overflow list (normally empty)
    u32 novf = min(*ovf_cnt, (u32)OVFCAP);
    for (u32 i = 0; i < novf; ++i) {
        if (ovf[2 * i + 1] == (u32)b) {
            u32 p = ovf[2 * i];
            u32 dl = p >> 17;
            if (dl == (u32)n0 || dl == (u32)(n0 + 64)) {
                float4 xv = x4[(size_t)(p & 0x1FFFFu) * 8 + q];
                if (dl == (u32)n0) { a0.x += xv.x; a0.y += xv.y; a0.z += xv.z; a0.w += xv.w; }
                else               { a1.x += xv.x; a1.y += xv.y; a1.z += xv.z; a1.w += xv.w; }
            }
        }
    }

    float4* o4 = (float4*)out;
    if (node0 + n0 < n_nodes)      o4[(size_t)node0 * 8 + t] = a0;
    if (node0 + n0 + 64 < n_nodes) o4[(size_t)node0 * 8 + 512 + t] = a1;
}

// ---------------- fallback (round-1 atomic path) ----------------

__global__ void __launch_bounds__(256)
mp_zero_kernel(float* __restrict__ out, int n) {
    int i = blockIdx.x * blockDim.x + threadIdx.x;
    if (i < n) out[i] = 0.0f;
}

__global__ void __launch_bounds__(256)
mp_scatter_kernel(const float* __restrict__ x, const int* __restrict__ src,
                  const int* __restrict__ dst, float* __restrict__ out,
                  int n_edges) {
    int idx = blockIdx.x * blockDim.x + threadIdx.x;
    if (idx >= n_edges * 8) return;
    int e = idx >> 3;
    int c = idx & 7;
    const float4 v = *reinterpret_cast<const float4*>(x + (size_t)src[e] * D_FEAT + c * 4);
    float* o = out + (size_t)dst[e] * D_FEAT + c * 4;
    unsafeAtomicAdd(o + 0, v.x);
    unsafeAtomicAdd(o + 1, v.y);
    unsafeAtomicAdd(o + 2, v.z);
    unsafeAtomicAdd(o + 3, v.w);
}

// ==================== launch ====================

extern "C" void kernel_launch(void* const* d_in, const int* in_sizes, int n_in,
                              void* d_out, int out_size, void* d_ws, size_t ws_size,
                              hipStream_t stream) {
    const float* x = (const float*)d_in[0];
    const int* edge_index = (const int*)d_in[1];
    int n_edges = in_sizes[1] / 2;
    const int* src = edge_index;            // row 0: source j
    const int* dst = edge_index + n_edges;  // row 1: target i
    float* out = (float*)d_out;
    int n_nodes = out_size / D_FEAT;

    int nb = (n_nodes + BKT_NODES - 1) >> BKT_SHIFT;     // 782

    if (nb <= MAX_NB && n_nodes <= (1 << 17)) {
        const int ncand[3] = {512, 384, 256};
        for (int ci = 0; ci < 3; ++ci) {
            int nsub = ncand[ci];
            int chunk = (n_edges + nsub - 1) / nsub;
            size_t need = ((size_t)nsub * nb                      // cnt
                           + 16                                   // ovf_cnt (padded)
                           + 2 * (size_t)OVFCAP                   // ovf list
                           + (((size_t)nb * nsub) << CAPSH))      // bin (bucket-major)
                          * sizeof(u32);
            if (need > ws_size) continue;

            u32* cnt     = (u32*)d_ws;
            u32* ovf_cnt = cnt + (size_t)nsub * nb;
            u32* ovf     = ovf_cnt + 16;
            u32* bin     = ovf + 2 * (size_t)OVFCAP;

            hipMemsetAsync(ovf_cnt, 0, sizeof(u32), stream);
            k_scatter3<<<nsub, 512, 0, stream>>>(src, dst, cnt, bin, ovf, ovf_cnt,
                                                 n_edges, nb, nsub, chunk);
            k_gather3<<<nb, 512, 0, stream>>>(x, cnt, bin, ovf, ovf_cnt, out,
                                              n_nodes, nb, nsub);
            return;
        }
    }

    // last-resort: atomic path
    mp_zero_kernel<<<(out_size + 255) / 256, 256, 0, stream>>>(out, out_size);
    int total_thr = n_edges * 8;
    mp_scatter_kernel<<<(total_thr + 255) / 256, 256, 0, stream>>>(x, src, dst, out, n_edges);
}

// Round 10
// 116.343 us; speedup vs baseline: 4.7146x; 1.0812x over previous
//
#include <hip/hip_runtime.h>

// out[d] = sum_{e: dst[e]==d} x[src[e]]   (N=100k, E=1.6M, D=32 f32)
//
// Round-9 lesson: scatter (~70us) is bound by 1.6M random 4B global stores
// (64 distinct lines per wave store = zero coalescing). Fix: build ALL
// sub-bins in LDS (nb x 16 slots = 50KB dynamic), then flush LDS->global as
// one coalesced uint4 stream. Per-edge cost: 1 LDS atomic + 1 LDS store.

#define D_FEAT 32
#define BKT_SHIFT 7
#define BKT_NODES 128
#define CAPSH 4               // 16 slots per sub-bin (64B = 1 line)
#define CAP (1 << CAPSH)
#define ECAP 4096             // packed entries per gather flush
#define OVFCAP 65536
typedef unsigned int u32;

// One block per edge-chunk. Stage sub-bins in LDS, flush coalesced.
// dynamic LDS: s_stage[nb*CAP] | s_cur[nb]
__global__ void __launch_bounds__(512)
k_scatter4(const int* __restrict__ src, const int* __restrict__ dst,
           u32* __restrict__ cnt, u32* __restrict__ bin,
           u32* __restrict__ ovf, u32* __restrict__ ovf_cnt,
           int n_edges, int nb, int nsub, int chunk) {
    extern __shared__ u32 smem[];
    u32* s_stage = smem;               // nb*CAP words, 16B aligned
    u32* s_cur   = smem + ((size_t)nb << CAPSH);
    int blk = blockIdx.x, t = threadIdx.x;
    for (int i = t; i < nb; i += 512) s_cur[i] = 0u;
    __syncthreads();
    int beg = blk * chunk, end = min(beg + chunk, n_edges);
    for (int e = beg + t; e < end; e += 512) {
        u32 d = (u32)dst[e];
        u32 b = d >> BKT_SHIFT;
        u32 pos = atomicAdd(&s_cur[b], 1u);          // LDS-only RMW
        u32 packed = (u32)src[e] | ((d & (BKT_NODES - 1)) << 17);
        if (pos < (u32)CAP) {
            s_stage[(b << CAPSH) + pos] = packed;    // LDS store, slot exclusive
        } else {
            u32 g = atomicAdd(ovf_cnt, 1u);          // ~never taken
            if (g < OVFCAP) { ovf[2 * g] = packed; ovf[2 * g + 1] = b; }
        }
    }
    __syncthreads();
    // coalesced flush: block-major bin[blk][b][slot]
    {
        int nquads = (nb << CAPSH) >> 2;
        uint4* gq = (uint4*)(bin + (((size_t)blk * nb) << CAPSH));
        const uint4* sq = (const uint4*)s_stage;
        for (int i = t; i < nquads; i += 512) gq[i] = sq[i];
    }
    u32* row = cnt + (size_t)blk * nb;
    for (int i = t; i < nb; i += 512) row[i] = min(s_cur[i], (u32)CAP);
}

// One block per bucket: counts -> scan -> pack quads -> sort by dlocal ->
// register accumulate (4-way unrolled for MLP).
__global__ void __launch_bounds__(512)
k_gather4(const float* __restrict__ x, const u32* __restrict__ cnt,
          const u32* __restrict__ bin, const u32* __restrict__ ovf,
          const u32* __restrict__ ovf_cnt, float* __restrict__ out,
          int n_nodes, int nb, int nsub) {
    __shared__ u32 s_cnt[512];
    __shared__ u32 s_sb[512];
    __shared__ u32 s_base[513];
    __shared__ u32 s_ent[ECAP];
    __shared__ u32 s_srt[ECAP];
    __shared__ u32 s_off[BKT_NODES + 1];
    __shared__ u32 s_cur[BKT_NODES];
    __shared__ u32 s_scan[BKT_NODES];
    int b = blockIdx.x, t = threadIdx.x;
    int node0 = b * BKT_NODES;
    const float4* x4 = (const float4*)x;
    const uint4* bin4 = (const uint4*)bin;
    int q = t & 7;
    int n0 = t >> 3;                       // nodes n0 and n0+64
    float4 a0 = make_float4(0.f, 0.f, 0.f, 0.f);
    float4 a1 = make_float4(0.f, 0.f, 0.f, 0.f);

    u32 c = 0u;
    if (t < nsub) c = min(cnt[(size_t)t * nb + b], (u32)CAP);
    s_cnt[t] = c;
    s_sb[t] = c;
    __syncthreads();
    for (int off = 1; off < 512; off <<= 1) {
        u32 y = (t >= off) ? s_sb[t - off] : 0u;
        __syncthreads();
        if (t >= off) s_sb[t] += y;
        __syncthreads();
    }
    s_base[t] = s_sb[t] - c;               // exclusive
    if (t == 511) s_base[512] = s_sb[511];
    __syncthreads();

    int subA = 0;
    u32 baseA = 0u;
    while (subA < nsub) {
        int lo = subA + 1, hi = nsub;
        while (lo < hi) {
            int mid = (lo + hi + 1) >> 1;
            if (s_base[mid] - baseA <= (u32)ECAP) lo = mid; else hi = mid - 1;
        }
        int subB = lo;
        int m = (int)(s_base[subB] - baseA);

        // pack sub-bins [subA,subB): 4 quads per sub-bin, read only used quads
        {
            int quads = (subB - subA) << (CAPSH - 2);
            for (int i = t; i < quads; i += 512) {
                int sub = subA + (i >> (CAPSH - 2));
                int k4 = i & ((1 << (CAPSH - 2)) - 1);
                int slot0 = k4 << 2;
                u32 cn = s_cnt[sub];
                if ((u32)slot0 < cn) {
                    uint4 v = bin4[(((size_t)sub * nb + b) << (CAPSH - 2)) + k4];
                    u32 base = (s_base[sub] - baseA) + slot0;
                    s_ent[base] = v.x;
                    if ((u32)(slot0 + 1) < cn) s_ent[base + 1] = v.y;
                    if ((u32)(slot0 + 2) < cn) s_ent[base + 2] = v.z;
                    if ((u32)(slot0 + 3) < cn) s_ent[base + 3] = v.w;
                }
            }
        }
        if (t < BKT_NODES) s_cur[t] = 0u;
        __syncthreads();

        for (int i = t; i < m; i += 512) atomicAdd(&s_cur[s_ent[i] >> 17], 1u);
        __syncthreads();
        u32 v = 0u;
        if (t < BKT_NODES) { v = s_cur[t]; s_scan[t] = v; }
        __syncthreads();
        for (int off = 1; off < BKT_NODES; off <<= 1) {
            u32 y = 0u;
            if (t < BKT_NODES && t >= off) y = s_scan[t - off];
            __syncthreads();
            if (t < BKT_NODES && t >= off) s_scan[t] += y;
            __syncthreads();
        }
        if (t < BKT_NODES) { u32 ex = s_scan[t] - v; s_off[t] = ex; s_cur[t] = ex; }
        if (t == BKT_NODES - 1) s_off[BKT_NODES] = s_scan[BKT_NODES - 1];
        __syncthreads();
        for (int i = t; i < m; i += 512) {
            u32 p = s_ent[i];
            u32 pos = atomicAdd(&s_cur[p >> 17], 1u);
            s_srt[pos] = p & 0x1FFFFu;
        }
        __syncthreads();

        // accumulate: 8 lanes share one 128B x-row; 4-way unroll for MLP
        {
            u32 j = s_off[n0], j1 = s_off[n0 + 1];
            for (; j + 3 < j1; j += 4) {
                float4 xa = x4[(size_t)s_srt[j] * 8 + q];
                float4 xb = x4[(size_t)s_srt[j + 1] * 8 + q];
                float4 xc = x4[(size_t)s_srt[j + 2] * 8 + q];
                float4 xd = x4[(size_t)s_srt[j + 3] * 8 + q];
                a0.x += xa.x + xb.x + xc.x + xd.x;
                a0.y += xa.y + xb.y + xc.y + xd.y;
                a0.z += xa.z + xb.z + xc.z + xd.z;
                a0.w += xa.w + xb.w + xc.w + xd.w;
            }
            for (; j < j1; ++j) {
                float4 xa = x4[(size_t)s_srt[j] * 8 + q];
                a0.x += xa.x; a0.y += xa.y; a0.z += xa.z; a0.w += xa.w;
            }
            j = s_off[n0 + 64]; j1 = s_off[n0 + 65];
            for (; j + 3 < j1; j += 4) {
                float4 xa = x4[(size_t)s_srt[j] * 8 + q];
                float4 xb = x4[(size_t)s_srt[j + 1] * 8 + q];
                float4 xc = x4[(size_t)s_srt[j + 2] * 8 + q];
                float4 xd = x4[(size_t)s_srt[j + 3] * 8 + q];
                a1.x += xa.x + xb.x + xc.x + xd.x;
                a1.y += xa.y + xb.y + xc.y + xd.y;
                a1.z += xa.z + xb.z + xc.z + xd.z;
                a1.w += xa.w + xb.w + xc.w + xd.w;
            }
            for (; j < j1; ++j) {
                float4 xa = x4[(size_t)s_srt[j] * 8 + q];
                a1.x += xa.x; a1.y += xa.y; a1.z += xa.z; a1.w += xa.w;
            }
        }
        __syncthreads();
        subA = subB;
        baseA = s_base[subB];
    }

    // replay overflow list (normally empty)
    u32 novf = min(*ovf_cnt, (u32)OVFCAP);
    for (u32 i = 0; i < novf; ++i) {
        if (ovf[2 * i + 1] == (u32)b) {
            u32 p = ovf[2 * i];
            u32 dl = p >> 17;
            if (dl == (u32)n0 || dl == (u32)(n0 + 64)) {
                float4 xv = x4[(size_t)(p & 0x1FFFFu) * 8 + q];
                if (dl == (u32)n0) { a0.x += xv.x; a0.y += xv.y; a0.z += xv.z; a0.w += xv.w; }
                else               { a1.x += xv.x; a1.y += xv.y; a1.z += xv.z; a1.w += xv.w; }
            }
        }
    }

    float4* o4 = (float4*)out;
    if (node0 + n0 < n_nodes)      o4[(size_t)node0 * 8 + t] = a0;
    if (node0 + n0 + 64 < n_nodes) o4[(size_t)node0 * 8 + 512 + t] = a1;
}

// ---------------- fallback (round-1 atomic path) ----------------

__global__ void __launch_bounds__(256)
mp_zero_kernel(float* __restrict__ out, int n) {
    int i = blockIdx.x * blockDim.x + threadIdx.x;
    if (i < n) out[i] = 0.0f;
}

__global__ void __launch_bounds__(256)
mp_scatter_kernel(const float* __restrict__ x, const int* __restrict__ src,
                  const int* __restrict__ dst, float* __restrict__ out,
                  int n_edges) {
    int idx = blockIdx.x * blockDim.x + threadIdx.x;
    if (idx >= n_edges * 8) return;
    int e = idx >> 3;
    int c = idx & 7;
    const float4 v = *reinterpret_cast<const float4*>(x + (size_t)src[e] * D_FEAT + c * 4);
    float* o = out + (size_t)dst[e] * D_FEAT + c * 4;
    unsafeAtomicAdd(o + 0, v.x);
    unsafeAtomicAdd(o + 1, v.y);
    unsafeAtomicAdd(o + 2, v.z);
    unsafeAtomicAdd(o + 3, v.w);
}

// ==================== launch ====================

extern "C" void kernel_launch(void* const* d_in, const int* in_sizes, int n_in,
                              void* d_out, int out_size, void* d_ws, size_t ws_size,
                              hipStream_t stream) {
    const float* x = (const float*)d_in[0];
    const int* edge_index = (const int*)d_in[1];
    int n_edges = in_sizes[1] / 2;
    const int* src = edge_index;            // row 0: source j
    const int* dst = edge_index + n_edges;  // row 1: target i
    float* out = (float*)d_out;
    int n_nodes = out_size / D_FEAT;

    int nb = (n_nodes + BKT_NODES - 1) >> BKT_SHIFT;     // 782

    // dynamic LDS for scatter: nb*CAP words stage + nb words cursors
    size_t sc_lds = ((size_t)nb * CAP + nb) * sizeof(u32);   // 53.2 KB @ nb=782

    if (n_nodes <= (1 << 17) && sc_lds <= 64 * 1024) {
        const int ncand[3] = {512, 384, 256};
        for (int ci = 0; ci < 3; ++ci) {
            int nsub = ncand[ci];
            int chunk = (n_edges + nsub - 1) / nsub;
            size_t need = ((size_t)nsub * nb                      // cnt
                           + 16                                   // ovf_cnt (padded)
                           + 2 * (size_t)OVFCAP                   // ovf list
                           + (((size_t)nsub * nb) << CAPSH))      // bin (block-major)
                          * sizeof(u32);
            if (need > ws_size) continue;

            u32* cnt     = (u32*)d_ws;
            u32* ovf_cnt = cnt + (size_t)nsub * nb;
            u32* ovf     = ovf_cnt + 16;
            u32* bin     = ovf + 2 * (size_t)OVFCAP;

            hipMemsetAsync(ovf_cnt, 0, sizeof(u32), stream);
            k_scatter4<<<nsub, 512, sc_lds, stream>>>(src, dst, cnt, bin, ovf, ovf_cnt,
                                                      n_edges, nb, nsub, chunk);
            k_gather4<<<nb, 512, 0, stream>>>(x, cnt, bin, ovf, ovf_cnt, out,
                                              n_nodes, nb, nsub);
            return;
        }
    }

    // last-resort: atomic path
    mp_zero_kernel<<<(out_size + 255) / 256, 256, 0, stream>>>(out, out_size);
    int total_thr = n_edges * 8;
    mp_scatter_kernel<<<(total_thr + 255) / 256, 256, 0, stream>>>(x, src, dst, out, n_edges);
}

// Round 11
// 112.381 us; speedup vs baseline: 4.8808x; 1.0353x over previous
//
#include <hip/hip_runtime.h>

// out[d] = sum_{e: dst[e]==d} x[src[e]]   (N=100k, E=1.6M, D=32 f32)
//
// Round-10 lesson: the 4-byte hipMemsetAsync dispatch costs a ~43us graph
// slot. Round 11: (1) per-block overflow regions (ovfn written every launch)
// -> no memset, 2-kernel graph; (2) bucket-major bin + count-gated flush ->
// gather reads one sequential stream, ~9MB instead of 25.6MB; (3) shfl-based
// scans -> ~25 fewer barriers per gather block.

#define D_FEAT 32
#define BKT_SHIFT 7
#define BKT_NODES 128
#define CAPSH 4               // 16 slots per sub-bin (64B = 1 line)
#define CAP (1 << CAPSH)
#define ECAP 4096             // packed entries per gather flush
#define OVFB 512              // overflow pairs per scatter block
typedef unsigned int u32;

// One block per edge-chunk. Stage sub-bins in LDS, gated bucket-major flush.
// dynamic LDS: s_stage[nb*CAP] | s_cur[nb]
__global__ void __launch_bounds__(512)
k_scatter5(const int* __restrict__ src, const int* __restrict__ dst,
           u32* __restrict__ cnt, u32* __restrict__ bin,
           u32* __restrict__ ovfb, u32* __restrict__ ovfn,
           int n_edges, int nb, int nsub, int chunk) {
    extern __shared__ u32 smem[];
    u32* s_stage = smem;                           // nb*CAP words
    u32* s_cur   = smem + ((size_t)nb << CAPSH);   // nb words
    __shared__ u32 s_ovf_n;
    int blk = blockIdx.x, t = threadIdx.x;
    for (int i = t; i < nb; i += 512) s_cur[i] = 0u;
    if (t == 0) s_ovf_n = 0u;
    __syncthreads();
    int beg = blk * chunk, end = min(beg + chunk, n_edges);
    for (int e = beg + t; e < end; e += 512) {
        u32 d = (u32)dst[e];
        u32 b = d >> BKT_SHIFT;
        u32 pos = atomicAdd(&s_cur[b], 1u);          // LDS-only RMW
        u32 packed = (u32)src[e] | ((d & (BKT_NODES - 1)) << 17);
        if (pos < (u32)CAP) {
            s_stage[(b << CAPSH) + pos] = packed;
        } else {
            u32 g = atomicAdd(&s_ovf_n, 1u);         // ~never taken
            if (g < (u32)OVFB) {
                ovfb[((size_t)blk * OVFB + g) * 2]     = packed;
                ovfb[((size_t)blk * OVFB + g) * 2 + 1] = (u32)b;
            }
        }
    }
    __syncthreads();
    // gated bucket-major flush: bin[b][blk][slot]; only quads with data
    {
        const uint4* sq = (const uint4*)s_stage;
        uint4* gq = (uint4*)bin;
        int nquads = nb << (CAPSH - 2);
        for (int i = t; i < nquads; i += 512) {
            int b  = i >> (CAPSH - 2);
            int k4 = i & ((1 << (CAPSH - 2)) - 1);
            u32 cn = min(s_cur[b], (u32)CAP);
            if ((u32)(k4 << 2) < cn)
                gq[(((size_t)b * nsub + blk) << (CAPSH - 2)) + k4] = sq[i];
        }
    }
    u32* row = cnt + (size_t)blk * nb;
    for (int i = t; i < nb; i += 512) row[i] = min(s_cur[i], (u32)CAP);
    if (t == 0) ovfn[blk] = min(s_ovf_n, (u32)OVFB);
}

// One block per bucket: counts -> shfl-scan -> sequential gated pack ->
// sort by dlocal (shfl-scan) -> register accumulate (4-way unrolled).
__global__ void __launch_bounds__(512)
k_gather5(const float* __restrict__ x, const u32* __restrict__ cnt,
          const u32* __restrict__ bin, const u32* __restrict__ ovfb,
          const u32* __restrict__ ovfn, float* __restrict__ out,
          int n_nodes, int nb, int nsub) {
    __shared__ u32 s_cnt[512];
    __shared__ u32 s_base[513];
    __shared__ u32 s_wsum[8];
    __shared__ u32 s_ent[ECAP];
    __shared__ u32 s_srt[ECAP];
    __shared__ u32 s_off[BKT_NODES + 1];
    __shared__ u32 s_cur[BKT_NODES];
    __shared__ u32 s_has;
    int b = blockIdx.x, t = threadIdx.x;
    int lane = t & 63, wid = t >> 6;
    int node0 = b * BKT_NODES;
    const float4* x4 = (const float4*)x;
    const uint4* bin4 = (const uint4*)bin;
    int q = t & 7;
    int n0 = t >> 3;                       // nodes n0 and n0+64
    float4 a0 = make_float4(0.f, 0.f, 0.f, 0.f);
    float4 a1 = make_float4(0.f, 0.f, 0.f, 0.f);

    // sub-bin counts + exclusive scan (wave shfl + cross-wave fix)
    u32 c = (t < nsub) ? min(cnt[(size_t)t * nb + b], (u32)CAP) : 0u;
    u32 myovf = (t < nsub) ? ovfn[t] : 0u;
    s_cnt[t] = c;
    if (t == 0) s_has = 0u;
    u32 s = c;
    #pragma unroll
    for (int off = 1; off < 64; off <<= 1) {
        u32 y = __shfl_up(s, off, 64);
        if (lane >= off) s += y;
    }
    if (lane == 63) s_wsum[wid] = s;
    __syncthreads();
    if (t == 0) {
        u32 run = 0u;
        #pragma unroll
        for (int w = 0; w < 8; ++w) { u32 v = s_wsum[w]; s_wsum[w] = run; run += v; }
    }
    if (myovf) atomicOr(&s_has, 1u);
    __syncthreads();
    u32 incl = s + s_wsum[wid];
    s_base[t] = incl - c;                  // exclusive
    if (t == 511) s_base[512] = incl;
    __syncthreads();

    int subA = 0;
    u32 baseA = 0u;
    while (subA < nsub) {
        // largest subB with base[subB]-baseA <= ECAP
        int lo = subA + 1, hi = nsub;
        while (lo < hi) {
            int mid = (lo + hi + 1) >> 1;
            if (s_base[mid] - baseA <= (u32)ECAP) lo = mid; else hi = mid - 1;
        }
        int subB = lo;
        int m = (int)(s_base[subB] - baseA);

        // pack sub-bins [subA,subB): sequential gated uint4 stream
        {
            int quads = (subB - subA) << (CAPSH - 2);
            size_t qbase = ((size_t)b * nsub + subA) << (CAPSH - 2);
            for (int i = t; i < quads; i += 512) {
                int sub = subA + (i >> (CAPSH - 2));
                int slot0 = (i & ((1 << (CAPSH - 2)) - 1)) << 2;
                u32 cn = s_cnt[sub];
                if ((u32)slot0 < cn) {
                    uint4 v = bin4[qbase + i];
                    u32 base = (s_base[sub] - baseA) + slot0;
                    s_ent[base] = v.x;
                    if ((u32)(slot0 + 1) < cn) s_ent[base + 1] = v.y;
                    if ((u32)(slot0 + 2) < cn) s_ent[base + 2] = v.z;
                    if ((u32)(slot0 + 3) < cn) s_ent[base + 3] = v.w;
                }
            }
        }
        if (t < BKT_NODES) s_cur[t] = 0u;
        __syncthreads();

        // count by dlocal
        for (int i = t; i < m; i += 512) atomicAdd(&s_cur[s_ent[i] >> 17], 1u);
        __syncthreads();

        // 128-entry exclusive scan by wave 0 (2 entries/lane, shfl)
        if (wid == 0) {
            u32 v0 = s_cur[2 * lane], v1 = s_cur[2 * lane + 1];
            u32 ps = v0 + v1;
            #pragma unroll
            for (int off = 1; off < 64; off <<= 1) {
                u32 y = __shfl_up(ps, off, 64);
                if (lane >= off) ps += y;
            }
            u32 ex = ps - (v0 + v1);
            s_off[2 * lane] = ex;     s_cur[2 * lane] = ex;
            s_off[2 * lane + 1] = ex + v0; s_cur[2 * lane + 1] = ex + v0;
            if (lane == 63) s_off[BKT_NODES] = ps;
        }
        __syncthreads();

        // rank into s_srt
        for (int i = t; i < m; i += 512) {
            u32 p = s_ent[i];
            u32 pos = atomicAdd(&s_cur[p >> 17], 1u);
            s_srt[pos] = p & 0x1FFFFu;
        }
        __syncthreads();

        // accumulate: 8 lanes share one 128B x-row; 4-way unroll for MLP
        {
            u32 j = s_off[n0], j1 = s_off[n0 + 1];
            for (; j + 3 < j1; j += 4) {
                float4 xa = x4[(size_t)s_srt[j] * 8 + q];
                float4 xb = x4[(size_t)s_srt[j + 1] * 8 + q];
                float4 xc = x4[(size_t)s_srt[j + 2] * 8 + q];
                float4 xd = x4[(size_t)s_srt[j + 3] * 8 + q];
                a0.x += xa.x + xb.x + xc.x + xd.x;
                a0.y += xa.y + xb.y + xc.y + xd.y;
                a0.z += xa.z + xb.z + xc.z + xd.z;
                a0.w += xa.w + xb.w + xc.w + xd.w;
            }
            for (; j < j1; ++j) {
                float4 xa = x4[(size_t)s_srt[j] * 8 + q];
                a0.x += xa.x; a0.y += xa.y; a0.z += xa.z; a0.w += xa.w;
            }
            j = s_off[n0 + 64]; j1 = s_off[n0 + 65];
            for (; j + 3 < j1; j += 4) {
                float4 xa = x4[(size_t)s_srt[j] * 8 + q];
                float4 xb = x4[(size_t)s_srt[j + 1] * 8 + q];
                float4 xc = x4[(size_t)s_srt[j + 2] * 8 + q];
                float4 xd = x4[(size_t)s_srt[j + 3] * 8 + q];
                a1.x += xa.x + xb.x + xc.x + xd.x;
                a1.y += xa.y + xb.y + xc.y + xd.y;
                a1.z += xa.z + xb.z + xc.z + xd.z;
                a1.w += xa.w + xb.w + xc.w + xd.w;
            }
            for (; j < j1; ++j) {
                float4 xa = x4[(size_t)s_srt[j] * 8 + q];
                a1.x += xa.x; a1.y += xa.y; a1.z += xa.z; a1.w += xa.w;
            }
        }
        __syncthreads();
        subA = subB;
        baseA = s_base[subB];
    }

    // replay per-block overflow lists (normally all empty)
    if (s_has) {
        for (int sub = 0; sub < nsub; ++sub) {
            u32 n = ovfn[sub];
            for (u32 i = 0; i < n; ++i) {
                u32 ob = ovfb[((size_t)sub * OVFB + i) * 2 + 1];
                if (ob == (u32)b) {
                    u32 p = ovfb[((size_t)sub * OVFB + i) * 2];
                    u32 dl = p >> 17;
                    if (dl == (u32)n0 || dl == (u32)(n0 + 64)) {
                        float4 xv = x4[(size_t)(p & 0x1FFFFu) * 8 + q];
                        if (dl == (u32)n0) { a0.x += xv.x; a0.y += xv.y; a0.z += xv.z; a0.w += xv.w; }
                        else               { a1.x += xv.x; a1.y += xv.y; a1.z += xv.z; a1.w += xv.w; }
                    }
                }
            }
        }
    }

    float4* o4 = (float4*)out;
    if (node0 + n0 < n_nodes)      o4[(size_t)node0 * 8 + t] = a0;
    if (node0 + n0 + 64 < n_nodes) o4[(size_t)node0 * 8 + 512 + t] = a1;
}

// ---------------- fallback (round-1 atomic path) ----------------

__global__ void __launch_bounds__(256)
mp_zero_kernel(float* __restrict__ out, int n) {
    int i = blockIdx.x * blockDim.x + threadIdx.x;
    if (i < n) out[i] = 0.0f;
}

__global__ void __launch_bounds__(256)
mp_scatter_kernel(const float* __restrict__ x, const int* __restrict__ src,
                  const int* __restrict__ dst, float* __restrict__ out,
                  int n_edges) {
    int idx = blockIdx.x * blockDim.x + threadIdx.x;
    if (idx >= n_edges * 8) return;
    int e = idx >> 3;
    int c = idx & 7;
    const float4 v = *reinterpret_cast<const float4*>(x + (size_t)src[e] * D_FEAT + c * 4);
    float* o = out + (size_t)dst[e] * D_FEAT + c * 4;
    unsafeAtomicAdd(o + 0, v.x);
    unsafeAtomicAdd(o + 1, v.y);
    unsafeAtomicAdd(o + 2, v.z);
    unsafeAtomicAdd(o + 3, v.w);
}

// ==================== launch ====================

extern "C" void kernel_launch(void* const* d_in, const int* in_sizes, int n_in,
                              void* d_out, int out_size, void* d_ws, size_t ws_size,
                              hipStream_t stream) {
    const float* x = (const float*)d_in[0];
    const int* edge_index = (const int*)d_in[1];
    int n_edges = in_sizes[1] / 2;
    const int* src = edge_index;            // row 0: source j
    const int* dst = edge_index + n_edges;  // row 1: target i
    float* out = (float*)d_out;
    int n_nodes = out_size / D_FEAT;

    int nb = (n_nodes + BKT_NODES - 1) >> BKT_SHIFT;     // 782

    // dynamic LDS for scatter: nb*CAP stage + nb cursors
    size_t sc_lds = ((size_t)nb * CAP + nb) * sizeof(u32);   // 53.2 KB @ nb=782

    if (n_nodes <= (1 << 17) && sc_lds <= 64 * 1024) {
        const int ncand[3] = {512, 384, 256};
        for (int ci = 0; ci < 3; ++ci) {
            int nsub = ncand[ci];
            int chunk = (n_edges + nsub - 1) / nsub;
            size_t need = ((size_t)nsub * nb                      // cnt
                           + 512                                  // ovfn
                           + 2 * (size_t)nsub * OVFB              // ovfb
                           + (((size_t)nb * nsub) << CAPSH))      // bin (bucket-major)
                          * sizeof(u32);
            if (need > ws_size) continue;

            u32* cnt  = (u32*)d_ws;
            u32* ovfn = cnt + (size_t)nsub * nb;
            u32* ovfb = ovfn + 512;
            u32* bin  = ovfb + 2 * (size_t)nsub * OVFB;

            k_scatter5<<<nsub, 512, sc_lds, stream>>>(src, dst, cnt, bin, ovfb, ovfn,
                                                      n_edges, nb, nsub, chunk);
            k_gather5<<<nb, 512, 0, stream>>>(x, cnt, bin, ovfb, ovfn, out,
                                              n_nodes, nb, nsub);
            return;
        }
    }

    // last-resort: atomic path
    mp_zero_kernel<<<(out_size + 255) / 256, 256, 0, stream>>>(out, out_size);
    int total_thr = n_edges * 8;
    mp_scatter_kernel<<<(total_thr + 255) / 256, 256, 0, stream>>>(x, src, dst, out, n_edges);
}